// Round 8
// baseline (325.063 us; speedup 1.0000x reference)
//
#include <hip/hip_runtime.h>

// ---------------- problem constants ----------------
#define N_NODES 5120
#define C_DIM   128
#define D_PE    16
#define M_MAX   256
#define B_G     32
#define H_HEADS 8
#define DH      16
#define EPS_PE  1e-8f
#define QT      2
#define SCP     264   // padded score stride (kills PV bank conflict)

// ---------------- ws layout (float units) ----------------
#define WS_COUNTS   0          // 32 i32
#define WS_OFFSETS  32         // 32 i32
#define WS_INTRA    64         // 5120 i32
#define WS_MASK     5184       // 8192 i32
#define WS_CN       13376      // B*M*32 f32 = 262144
#define WS_PN       275520     // B*M*16 f32 = 131072
#define WS_KFHI     406592     // B*M*64 bf16 = 262144 f
#define WS_KFLO     668736     // B*M*32 bf16 = 131072 f
#define WS_QM       799808     // 1048576
#define WS_KM       1848384
#define WS_VM       2896960
#define WS_OATT     3945536
#define WS_HLN      4994112    // 655360
#define WS_FFNH     5649472    // 1310720
#define WS_BIAS     6960192    // B*M*M*8 bf16 = 8388608 f
#define WS_WPK_HI   15348800   // 131072 shorts = 65536 f
#define WS_WPK_LO   15414336   // 65536 f
#define WS_ZERO_FLOATS 13376   // counts..mask zeroed each call

// packed-weight offsets (shorts)
#define WOFF_O   49152
#define WOFF_W1  65536
#define WOFF_W2  98304

typedef __attribute__((ext_vector_type(8))) short bf8_t;
typedef __attribute__((ext_vector_type(4))) float f4_t;

__device__ inline short f2bf(float f) {
    union { float f; unsigned u; } v; v.f = f;
    unsigned r = (v.u + 0x7FFF + ((v.u >> 16) & 1)) >> 16;
    return (short)r;
}
__device__ inline float bf2f(short h) {
    union { unsigned u; float f; } v; v.u = ((unsigned)(unsigned short)h) << 16;
    return v.f;
}
__device__ inline unsigned pack2(short a, short b) {
    return (unsigned)(unsigned short)a | ((unsigned)(unsigned short)b << 16);
}
__device__ inline bf8_t bf8_from2(uint2 a, uint2 b) {
    bf8_t o;
    o[0]=(short)a.x; o[1]=(short)(a.x>>16); o[2]=(short)a.y; o[3]=(short)(a.y>>16);
    o[4]=(short)b.x; o[5]=(short)(b.x>>16); o[6]=(short)b.y; o[7]=(short)(b.y>>16);
    return o;
}

// ---------------- setup: counts -> offsets -> intra ----------------
__global__ __launch_bounds__(256) void setup_kernel(
    const int* __restrict__ batch, int* __restrict__ counts_o,
    int* __restrict__ offsets, int* __restrict__ intra)
{
    __shared__ int cnt[B_G];
    __shared__ int off[B_G];
    const int t = threadIdx.x;
    if (t < B_G) cnt[t] = 0;
    __syncthreads();
    for (int n = t; n < N_NODES; n += 256) atomicAdd(&cnt[batch[n]], 1);
    __syncthreads();
    if (t == 0) { int s = 0; for (int b = 0; b < B_G; ++b) { off[b] = s; s += cnt[b]; } }
    __syncthreads();
    if (t < B_G) { offsets[t] = off[t]; counts_o[t] = cnt[t]; }
    for (int n = t; n < N_NODES; n += 256) intra[n] = n - off[batch[n]];
}

// ---------------- prep: per-node pe -> dense pn/cn/kf + mask ----------------
__global__ __launch_bounds__(256) void prep_kernel(
    const float* __restrict__ pre, const float* __restrict__ pim,
    const int* __restrict__ batch, const int* __restrict__ intra,
    float* __restrict__ pn, float* __restrict__ cn,
    unsigned short* __restrict__ kf_hi, unsigned short* __restrict__ kf_lo,
    int* __restrict__ mask)
{
    const int idx = blockIdx.x * 256 + threadIdx.x;   // N_NODES*16 = 81920
    const int n = idx >> 4, dd = idx & 15;
    const int b = batch[n], m = intra[n];
    const size_t cell = (size_t)b * M_MAX + m;
    const float a = pre[(size_t)n * D_PE + dd], bb = pim[(size_t)n * D_PE + dd];
    const float p = sqrtf(a * a + bb * bb + EPS_PE);
    const float inv = 1.f / p;
    const float cr = a * inv, ci = bb * inv;
    pn[cell * 16 + dd] = p;
    cn[cell * 32 + dd]      = cr;
    cn[cell * 32 + 16 + dd] = ci;
    const size_t hb = cell * 64, lb = cell * 32;
    short crh = f2bf(cr), cih = f2bf(ci);
    kf_hi[hb + dd]      = (unsigned short)crh;
    kf_hi[hb + 16 + dd] = (unsigned short)cih;
    kf_hi[hb + 32 + dd] = (unsigned short)f2bf(p);
    kf_hi[hb + 48 + dd] = (dd == 0) ? (unsigned short)f2bf(1.f) : 0;
    kf_lo[lb + dd]      = (unsigned short)f2bf(cr - bf2f(crh));
    kf_lo[lb + 16 + dd] = (unsigned short)f2bf(ci - bf2f(cih));
    if (dd == 0) mask[cell] = 1;
}

// ---------------- weight packing (unchanged, validated) ----------------
__global__ __launch_bounds__(256) void wpack_kernel(
    const float* __restrict__ wq, const float* __restrict__ wk,
    const float* __restrict__ wv, const float* __restrict__ wo,
    const float* __restrict__ w1, const float* __restrict__ w2,
    unsigned short* __restrict__ hi, unsigned short* __restrict__ lo)
{
    const int tid = blockIdx.x * 256 + threadIdx.x;
    const int tile = tid >> 6, lane = tid & 63;
    const float* W; int N, ltile; size_t off;
    if (tile < 128) {
        const int wi = tile >> 5; ltile = tile & 31; N = 128;
        W = (wi == 0) ? wq : (wi == 1) ? wk : (wi == 2) ? wv : wo;
        off = (size_t)wi * 16384;
    } else if (tile < 192) { ltile = tile - 128; N = 256; W = w1; off = WOFF_W1; }
    else                   { ltile = tile - 192; N = 128; W = w2; off = WOFF_W2; }
    const int NT = N / 16;
    const int kt = ltile / NT, nt = ltile % NT;
    const int col = nt * 16 + (lane & 15);
    const int k0  = kt * 32 + (lane >> 4) * 8;
    bf8_t vhi, vlo;
    #pragma unroll
    for (int e = 0; e < 8; ++e) {
        const float v = W[(size_t)(k0 + e) * N + col];
        const short h = f2bf(v);
        vhi[e] = h; vlo[e] = f2bf(v - bf2f(h));
    }
    const size_t toff = off + ((size_t)ltile * 64 + lane) * 8;
    *(bf8_t*)(hi + toff) = vhi;
    *(bf8_t*)(lo + toff) = vlo;
}

// ---------------- MFMA core: acc[NT] = Arows @ W (split bf16) ----------------
template<int K, int N>
__device__ inline void mgemm_core(
    const float* __restrict__ Arow,  // points at A row `arow` (stride K)
    const unsigned short* __restrict__ hi, const unsigned short* __restrict__ lo,
    int lane, f4_t* acc)
{
    constexpr int NT = N / 16, KT = K / 32;
    const int g = lane >> 4;
    #pragma unroll
    for (int kt = 0; kt < KT; ++kt) {
        const float* ap = Arow + kt * 32 + g * 8;
        const float4 a0 = *(const float4*)ap;
        const float4 a1 = *(const float4*)(ap + 4);
        const float av[8] = {a0.x, a0.y, a0.z, a0.w, a1.x, a1.y, a1.z, a1.w};
        bf8_t ahi, alo;
        #pragma unroll
        for (int e = 0; e < 8; ++e) {
            const short h = f2bf(av[e]);
            ahi[e] = h; alo[e] = f2bf(av[e] - bf2f(h));
        }
        #pragma unroll
        for (int nt = 0; nt < NT; ++nt) {
            const size_t toff = ((size_t)(kt * NT + nt) * 64 + lane) * 8;
            const bf8_t bhi = *(const bf8_t*)(hi + toff);
            const bf8_t blo = *(const bf8_t*)(lo + toff);
            acc[nt] = __builtin_amdgcn_mfma_f32_16x16x32_bf16(ahi, bhi, acc[nt], 0, 0, 0);
            acc[nt] = __builtin_amdgcn_mfma_f32_16x16x32_bf16(alo, bhi, acc[nt], 0, 0, 0);
            acc[nt] = __builtin_amdgcn_mfma_f32_16x16x32_bf16(ahi, blo, acc[nt], 0, 0, 0);
        }
    }
}

// ---------------- QKV over nodes, scatter-write to dense ----------------
__global__ __launch_bounds__(256) void qkv_node_kernel(
    const float* __restrict__ x,
    const unsigned short* __restrict__ hi, const unsigned short* __restrict__ lo,
    const float* __restrict__ bq, const float* __restrict__ bk, const float* __restrict__ bv,
    const int* __restrict__ batch, const int* __restrict__ intra,
    float* __restrict__ qm, float* __restrict__ km, float* __restrict__ vm)
{
    const int sel = blockIdx.y;
    const float* bias = (sel == 0) ? bq : (sel == 1) ? bk : bv;
    float* out = (sel == 0) ? qm : (sel == 1) ? km : vm;
    const unsigned short* whi = hi + (size_t)sel * 16384;
    const unsigned short* wlo = lo + (size_t)sel * 16384;

    const int rb = blockIdx.x * 64;
    const int w = threadIdx.x >> 6, lane = threadIdx.x & 63;
    const int lj = lane & 15, g = lane >> 4;
    const int arow = rb + w * 16 + lj;   // node

    f4_t acc[8];
    #pragma unroll
    for (int nt = 0; nt < 8; ++nt) acc[nt] = (f4_t){0.f, 0.f, 0.f, 0.f};
    mgemm_core<128, 128>(x + (size_t)arow * 128, whi, wlo, lane, acc);

    const int orow0 = rb + w * 16 + g * 4;
    int dst[4];
    #pragma unroll
    for (int r = 0; r < 4; ++r) {
        const int nr = orow0 + r;
        dst[r] = batch[nr] * M_MAX + intra[nr];
    }
    #pragma unroll
    for (int nt = 0; nt < 8; ++nt) {
        const int col = nt * 16 + lj;
        const float bv_ = bias[col];
        #pragma unroll
        for (int r = 0; r < 4; ++r)
            out[(size_t)dst[r] * 128 + col] = acc[nt][r] + bv_;
    }
}

// ---------------- plain MFMA GEMM (ffn1) ----------------
template<int K, int N, bool RELU>
__global__ __launch_bounds__(256) void mgemm_kernel(
    const float* __restrict__ A,
    const unsigned short* __restrict__ hi, const unsigned short* __restrict__ lo,
    const float* __restrict__ bias, float* __restrict__ out)
{
    constexpr int NT = N / 16;
    const int rb = blockIdx.x * 64;
    const int w = threadIdx.x >> 6, lane = threadIdx.x & 63;
    const int lj = lane & 15, g = lane >> 4;
    const int arow = rb + w * 16 + lj;

    f4_t acc[NT];
    #pragma unroll
    for (int nt = 0; nt < NT; ++nt) acc[nt] = (f4_t){0.f, 0.f, 0.f, 0.f};
    mgemm_core<K, N>(A + (size_t)arow * K, hi, lo, lane, acc);

    const int orow0 = rb + w * 16 + g * 4;
    #pragma unroll
    for (int nt = 0; nt < NT; ++nt) {
        const int col = nt * 16 + lj;
        const float bv = bias[col];
        #pragma unroll
        for (int r = 0; r < 4; ++r) {
            float v = acc[nt][r] + bv;
            if (RELU) v = fmaxf(v, 0.f);
            out[(size_t)(orow0 + r) * N + col] = v;
        }
    }
}

// ---------------- GEMM + residual + LayerNorm fused (o-proj/ln2, ffn2/ln3) ----------------
// GATHER_A: A row = src[bm(node)] else A row = node. res: x (oproj) / hln (ffn2).
template<int K, bool GATHER_A>
__global__ __launch_bounds__(256) void gemm_res_ln_kernel(
    const float* __restrict__ A,
    const unsigned short* __restrict__ hi, const unsigned short* __restrict__ lo,
    const float* __restrict__ bias, const float* __restrict__ res,
    const int* __restrict__ batch, const int* __restrict__ intra,
    const float* __restrict__ lng, const float* __restrict__ lnb,
    float* __restrict__ out)
{
    __shared__ float sOut[64][133];
    __shared__ float red_s[64][4];
    __shared__ float red_q[64][4];

    const int rb = blockIdx.x * 64;
    const int w = threadIdx.x >> 6, lane = threadIdx.x & 63;
    const int lj = lane & 15, g = lane >> 4;
    const int arow = rb + w * 16 + lj;   // node
    const size_t asrc = GATHER_A ? (size_t)(batch[arow] * M_MAX + intra[arow]) : (size_t)arow;

    f4_t acc[8];
    #pragma unroll
    for (int nt = 0; nt < 8; ++nt) acc[nt] = (f4_t){0.f, 0.f, 0.f, 0.f};
    mgemm_core<K, 128>(A + asrc * K, hi, lo, lane, acc);

    const int lrow0 = w * 16 + g * 4;
    #pragma unroll
    for (int nt = 0; nt < 8; ++nt) {
        const int col = nt * 16 + lj;
        const float bv = bias[col];
        #pragma unroll
        for (int r = 0; r < 4; ++r)
            sOut[lrow0 + r][col] = acc[nt][r] + bv;
    }
    __syncthreads();

    const int row = threadIdx.x >> 2, seg = threadIdx.x & 3;
    const int n = rb + row;
    float s = 0.f, sq = 0.f;
    #pragma unroll
    for (int i = 0; i < 32; ++i) {
        const int c = 4 * i + seg;
        const float v = sOut[row][c] + res[(size_t)n * 128 + c];
        sOut[row][c] = v;
        s += v; sq += v * v;
    }
    red_s[row][seg] = s; red_q[row][seg] = sq;
    __syncthreads();
    s  = red_s[row][0] + red_s[row][1] + red_s[row][2] + red_s[row][3];
    sq = red_q[row][0] + red_q[row][1] + red_q[row][2] + red_q[row][3];
    const float mu  = s * (1.f / 128.f);
    const float var = sq * (1.f / 128.f) - mu * mu;
    const float sc  = rsqrtf(var + 1e-5f);
    #pragma unroll
    for (int i = 0; i < 32; ++i) {
        const int c = 4 * i + seg;
        out[(size_t)n * 128 + c] = (sOut[row][c] - mu) * sc * lng[c] + lnb[c];
    }
}

// ---------------- MFMA pairwise-bias kernel (validated; + counts early-exit) ----------------
__global__ __launch_bounds__(512) void bias_kernel(
    const float* __restrict__ cn, const float* __restrict__ pn,
    const unsigned short* __restrict__ kf_hi, const unsigned short* __restrict__ kf_lo,
    const float* __restrict__ w1, const float* __restrict__ b1,
    const float* __restrict__ w2, const float* __restrict__ b2,
    const int* __restrict__ counts,
    unsigned short* __restrict__ bias_out)
{
    const int b  = blockIdx.y;
    const int i0 = blockIdx.x * 16;
    if (i0 >= counts[b]) return;

    __shared__ float sW1T[32][65];
    __shared__ float s_cn[16][32];
    __shared__ float s_pn[16][16];
    __shared__ uint2 s_scr[8][16][10];

    const int t  = threadIdx.x;

    for (int idx = t; idx < 2048; idx += 512) {
        int f = idx >> 5, hh = idx & 31;
        sW1T[hh][f] = w1[f * 32 + hh];
    }
    { int il = t >> 5, c = t & 31;
      s_cn[il][c] = cn[((size_t)(b * 256 + i0 + il)) * 32 + c]; }
    if (t < 256) { int il = t >> 4, dd = t & 15;
      s_pn[il][dd] = pn[((size_t)(b * 256 + i0 + il)) * 16 + dd]; }
    __syncthreads();

    const int w    = t >> 6;
    const int lane = t & 63;
    const int lj   = lane & 15;
    const int g    = lane >> 4;

    bf8_t a2f;
    #pragma unroll
    for (int e = 0; e < 8; ++e) {
        float v = (lj < 8) ? w2[(g * 8 + e) * 8 + lj] : 0.f;
        a2f[e] = f2bf(v);
    }
    float b2v0 = 0.f, b2v1 = 0.f, b2v2 = 0.f, b2v3 = 0.f;
    if (g < 2) { b2v0 = b2[g*4+0]; b2v1 = b2[g*4+1]; b2v2 = b2[g*4+2]; b2v3 = b2[g*4+3]; }

    for (int ii = 0; ii < 2; ++ii) {
        const int il = w * 2 + ii;
        const int i  = i0 + il;

        float vrow0 = b1[lj], vrow1 = b1[16 + lj];
        #pragma unroll
        for (int dd = 0; dd < 16; ++dd) {
            float p = s_pn[il][dd];
            vrow0 = fmaf(sW1T[lj][16 + dd],      p, vrow0);
            vrow1 = fmaf(sW1T[16 + lj][16 + dd], p, vrow1);
        }

        bf8_t a0hi0, a0lo0, a1f0, a0hi1, a0lo1, a1f1;
        #pragma unroll
        for (int e = 0; e < 8; ++e) {
            const int dd = (g & 1) * 8 + e;
            const float cr = s_cn[il][dd], ci = s_cn[il][16 + dd];
            {
                float wr = sW1T[lj][32 + dd], wi = sW1T[lj][48 + dd];
                float val = (g < 2) ? (wr * cr - wi * ci) : (wr * ci + wi * cr);
                short hi = f2bf(val);
                a0hi0[e] = hi; a0lo0[e] = f2bf(val - bf2f(hi));
                float v1 = (g < 2) ? sW1T[lj][g * 8 + e]
                                   : ((g == 2 && e == 0) ? vrow0 : 0.f);
                a1f0[e] = f2bf(v1);
            }
            {
                float wr = sW1T[16 + lj][32 + dd], wi = sW1T[16 + lj][48 + dd];
                float val = (g < 2) ? (wr * cr - wi * ci) : (wr * ci + wi * cr);
                short hi = f2bf(val);
                a0hi1[e] = hi; a0lo1[e] = f2bf(val - bf2f(hi));
                float v1 = (g < 2) ? sW1T[16 + lj][g * 8 + e]
                                   : ((g == 2 && e == 0) ? vrow1 : 0.f);
                a1f1[e] = f2bf(v1);
            }
        }

        for (int jt = 0; jt < 16; ++jt) {
            const size_t node = (size_t)b * 256 + jt * 16 + lj;
            const bf8_t* ph = (const bf8_t*)(kf_hi + node * 64);
            const bf8_t* pl = (const bf8_t*)(kf_lo + node * 32);
            bf8_t b0hi = ph[g];
            bf8_t b0lo = pl[g];
            bf8_t b1f  = ph[4 + g];

            f4_t acc0 = {0.f, 0.f, 0.f, 0.f}, acc1 = {0.f, 0.f, 0.f, 0.f};
            acc0 = __builtin_amdgcn_mfma_f32_16x16x32_bf16(a0hi0, b0hi, acc0, 0, 0, 0);
            acc0 = __builtin_amdgcn_mfma_f32_16x16x32_bf16(a0hi0, b0lo, acc0, 0, 0, 0);
            acc0 = __builtin_amdgcn_mfma_f32_16x16x32_bf16(a0lo0, b0hi, acc0, 0, 0, 0);
            acc0 = __builtin_amdgcn_mfma_f32_16x16x32_bf16(a1f0,  b1f,  acc0, 0, 0, 0);
            acc1 = __builtin_amdgcn_mfma_f32_16x16x32_bf16(a0hi1, b0hi, acc1, 0, 0, 0);
            acc1 = __builtin_amdgcn_mfma_f32_16x16x32_bf16(a0hi1, b0lo, acc1, 0, 0, 0);
            acc1 = __builtin_amdgcn_mfma_f32_16x16x32_bf16(a0lo1, b0hi, acc1, 0, 0, 0);
            acc1 = __builtin_amdgcn_mfma_f32_16x16x32_bf16(a1f1,  b1f,  acc1, 0, 0, 0);

            uint2 w0, w1p;
            w0.x  = pack2(f2bf(fmaxf(acc0[0], 0.f)), f2bf(fmaxf(acc0[1], 0.f)));
            w0.y  = pack2(f2bf(fmaxf(acc0[2], 0.f)), f2bf(fmaxf(acc0[3], 0.f)));
            w1p.x = pack2(f2bf(fmaxf(acc1[0], 0.f)), f2bf(fmaxf(acc1[1], 0.f)));
            w1p.y = pack2(f2bf(fmaxf(acc1[2], 0.f)), f2bf(fmaxf(acc1[3], 0.f)));
            s_scr[w][lj][g]     = w0;
            s_scr[w][lj][4 + g] = w1p;
            __builtin_amdgcn_s_waitcnt(0);

            uint2 q0 = s_scr[w][lj][2 * g];
            uint2 q1 = s_scr[w][lj][2 * g + 1];
            bf8_t hb = bf8_from2(q0, q1);

            f4_t acc2 = {0.f, 0.f, 0.f, 0.f};
            acc2 = __builtin_amdgcn_mfma_f32_16x16x32_bf16(a2f, hb, acc2, 0, 0, 0);

            if (g < 2) {
                uint2 st;
                st.x = pack2(f2bf(acc2[0] + b2v0), f2bf(acc2[1] + b2v1));
                st.y = pack2(f2bf(acc2[2] + b2v2), f2bf(acc2[3] + b2v3));
                size_t idx = (((size_t)b * 256 + i) * 256 + jt * 16 + lj) * 8 + g * 4;
                *(uint2*)(bias_out + idx) = st;
            }
        }
    }
}

// ---------------- attention (QT=2, counts early-exit) ----------------
__global__ __launch_bounds__(256) void attn_kernel(
    const float* __restrict__ qm, const float* __restrict__ km, const float* __restrict__ vm,
    const int* __restrict__ mask, const unsigned short* __restrict__ bias,
    const int* __restrict__ counts,
    float* __restrict__ o_att)
{
    const int b  = blockIdx.y;
    const int i0 = blockIdx.x * QT;
    if (i0 >= counts[b]) return;
    const int t  = threadIdx.x;
    const int j  = t;

    __shared__ float s_q[QT][C_DIM];
    __shared__ float s_sc[QT][H_HEADS][SCP];

    {   // stage QT*128 = 256 values
        const int qi = t >> 7, c = t & 127;
        s_q[qi][c] = qm[((size_t)(b * 256 + i0 + qi)) * C_DIM + c];
    }
    __syncthreads();

    const int mj = mask[b * M_MAX + j];
    uint4 bu[QT];
    #pragma unroll
    for (int qi = 0; qi < QT; ++qi)
        bu[qi] = *(const uint4*)(bias + (((size_t)(b * 256 + i0 + qi)) * 256 + j) * 8);

    const float* krow = km + ((size_t)(b * 256 + j)) * C_DIM;
    #pragma unroll
    for (int h = 0; h < 8; ++h) {
        float kv[DH];
        #pragma unroll
        for (int q4 = 0; q4 < 4; ++q4) {
            float4 v = ((const float4*)(krow + h * DH))[q4];
            kv[q4*4+0]=v.x; kv[q4*4+1]=v.y; kv[q4*4+2]=v.z; kv[q4*4+3]=v.w;
        }
        #pragma unroll
        for (int qi = 0; qi < QT; ++qi) {
            float dot = 0.f;
            #pragma unroll
            for (int dd = 0; dd < DH; ++dd)
                dot = fmaf(s_q[qi][h * DH + dd], kv[dd], dot);
            const unsigned u = ((const unsigned*)&bu[qi])[h >> 1];
            const float bv = bf2f((short)((h & 1) ? (u >> 16) : (u & 0xffff)));
            s_sc[qi][h][j] = mj ? fmaf(dot, 0.25f, bv) : -1e9f;
        }
    }
    __syncthreads();

    {   // softmax: QT*8 = 16 rows of 256
        const int wave = t >> 6, lane = t & 63;
        for (int r = wave; r < QT * H_HEADS; r += 4) {
            float* row = ((float*)s_sc) + r * SCP;
            float x0 = row[lane], x1 = row[lane + 64], x2 = row[lane + 128], x3 = row[lane + 192];
            float mx = fmaxf(fmaxf(x0, x1), fmaxf(x2, x3));
            #pragma unroll
            for (int off = 32; off > 0; off >>= 1) mx = fmaxf(mx, __shfl_xor(mx, off, 64));
            float e0 = expf(x0 - mx), e1 = expf(x1 - mx), e2 = expf(x2 - mx), e3 = expf(x3 - mx);
            float s = e0 + e1 + e2 + e3;
            #pragma unroll
            for (int off = 32; off > 0; off >>= 1) s += __shfl_xor(s, off, 64);
            const float inv = 1.f / s;
            row[lane] = e0 * inv; row[lane + 64] = e1 * inv;
            row[lane + 128] = e2 * inv; row[lane + 192] = e3 * inv;
        }
    }
    __syncthreads();

    {   // PV: thread (c, gq) -> 1 query row
        const int c = t & 127;
        const int gq = t >> 7;           // 0..1
        const int h = c >> 4;
        const float* vb = vm + (size_t)b * M_MAX * C_DIM + c;
        float a0 = 0.f;
        for (int jj = 0; jj < M_MAX; jj += 4) {
            float4 pA = *(const float4*)&s_sc[gq][h][jj];
            a0 = fmaf(pA.x, vb[(size_t)(jj + 0) * C_DIM], a0);
            a0 = fmaf(pA.y, vb[(size_t)(jj + 1) * C_DIM], a0);
            a0 = fmaf(pA.z, vb[(size_t)(jj + 2) * C_DIM], a0);
            a0 = fmaf(pA.w, vb[(size_t)(jj + 3) * C_DIM], a0);
        }
        o_att[((size_t)(b * 256 + i0 + gq)) * C_DIM + c] = a0;
    }
}

// ---------------- launch ----------------
extern "C" void kernel_launch(void* const* d_in, const int* in_sizes, int n_in,
                              void* d_out, int out_size, void* d_ws, size_t ws_size,
                              hipStream_t stream)
{
    const float* x      = (const float*)d_in[0];
    const float* pe_re  = (const float*)d_in[1];
    const float* pe_im  = (const float*)d_in[2];
    const float* wq     = (const float*)d_in[3];
    const float* bq     = (const float*)d_in[4];
    const float* wk     = (const float*)d_in[5];
    const float* bk     = (const float*)d_in[6];
    const float* wv     = (const float*)d_in[7];
    const float* bv     = (const float*)d_in[8];
    const float* wo     = (const float*)d_in[9];
    const float* bo     = (const float*)d_in[10];
    const float* pe_w1  = (const float*)d_in[11];
    const float* pe_b1  = (const float*)d_in[12];
    const float* pe_w2  = (const float*)d_in[13];
    const float* pe_b2  = (const float*)d_in[14];
    const float* mlp_w1 = (const float*)d_in[15];
    const float* mlp_b1 = (const float*)d_in[16];
    const float* mlp_w2 = (const float*)d_in[17];
    const float* mlp_b2 = (const float*)d_in[18];
    const float* ln2_g  = (const float*)d_in[19];
    const float* ln2_b  = (const float*)d_in[20];
    const float* ln3_g  = (const float*)d_in[21];
    const float* ln3_b  = (const float*)d_in[22];
    const int*   batch  = (const int*)d_in[23];

    float* ws = (float*)d_ws;
    int*   counts  = (int*)(ws + WS_COUNTS);
    int*   offsets = (int*)(ws + WS_OFFSETS);
    int*   intra   = (int*)(ws + WS_INTRA);
    int*   mask    = (int*)(ws + WS_MASK);
    float* cn   = ws + WS_CN;
    float* pn   = ws + WS_PN;
    unsigned short* kf_hi = (unsigned short*)(ws + WS_KFHI);
    unsigned short* kf_lo = (unsigned short*)(ws + WS_KFLO);
    float* qm   = ws + WS_QM;
    float* km   = ws + WS_KM;
    float* vm   = ws + WS_VM;
    float* oatt = ws + WS_OATT;
    float* hln  = ws + WS_HLN;
    float* ffnh = ws + WS_FFNH;
    unsigned short* bias = (unsigned short*)(ws + WS_BIAS);
    unsigned short* wpk_hi = (unsigned short*)(ws + WS_WPK_HI);
    unsigned short* wpk_lo = (unsigned short*)(ws + WS_WPK_LO);
    float* outp = (float*)d_out;

    hipMemsetAsync(d_ws, 0, (size_t)WS_ZERO_FLOATS * sizeof(float), stream);

    setup_kernel<<<1, 256, 0, stream>>>(batch, counts, offsets, intra);
    wpack_kernel<<<64, 256, 0, stream>>>(wq, wk, wv, wo, mlp_w1, mlp_w2, wpk_hi, wpk_lo);
    prep_kernel<<<320, 256, 0, stream>>>(pe_re, pe_im, batch, intra, pn, cn, kf_hi, kf_lo, mask);

    qkv_node_kernel<<<dim3(80, 3), 256, 0, stream>>>(x, wpk_hi, wpk_lo, bq, bk, bv,
                                                     batch, intra, qm, km, vm);

    bias_kernel<<<dim3(16, 32), 512, 0, stream>>>(cn, pn, kf_hi, kf_lo,
                                                  pe_w1, pe_b1, pe_w2, pe_b2, counts, bias);

    attn_kernel<<<dim3(M_MAX / QT, B_G), 256, 0, stream>>>(qm, km, vm, mask, bias, counts, oatt);

    gemm_res_ln_kernel<128, true><<<80, 256, 0, stream>>>(
        oatt, wpk_hi + WOFF_O, wpk_lo + WOFF_O, bo, x, batch, intra, ln2_g, ln2_b, hln);

    mgemm_kernel<128, 256, true><<<80, 256, 0, stream>>>(
        hln, wpk_hi + WOFF_W1, wpk_lo + WOFF_W1, mlp_b1, ffnh);

    gemm_res_ln_kernel<256, false><<<80, 256, 0, stream>>>(
        ffnh, wpk_hi + WOFF_W2, wpk_lo + WOFF_W2, mlp_b2, hln, batch, intra, ln3_g, ln3_b, outp);
}

// Round 9
// 296.065 us; speedup vs baseline: 1.0979x; 1.0979x over previous
//
#include <hip/hip_runtime.h>

// ---------------- problem constants ----------------
#define N_NODES 5120
#define C_DIM   128
#define D_PE    16
#define M_MAX   256
#define B_G     32
#define H_HEADS 8
#define DH      16
#define EPS_PE  1e-8f
#define QT      4
#define SCP     264   // padded score stride (kills PV bank conflict)

// ---------------- ws layout (float units) ----------------
#define WS_COUNTS   0          // 32 i32
#define WS_OFFSETS  32         // 32 i32
#define WS_INTRA    64         // 5120 i32
#define WS_MASK     5184       // 8192 i32
#define WS_CN       13376      // B*M*32 f32 = 262144
#define WS_PN       275520     // B*M*16 f32 = 131072
#define WS_KFHI     406592     // B*M*64 bf16 = 262144 f
#define WS_KFLO     668736     // B*M*32 bf16 = 131072 f
#define WS_QM       799808     // 1048576
#define WS_KM       1848384
#define WS_VM       2896960
#define WS_OATT     3945536
#define WS_HLN      4994112    // 655360
#define WS_FFNH     5649472    // 1310720
#define WS_BIAS     6960192    // B*M*M*8 bf16 = 8388608 f
#define WS_WPK_HI   15348800   // 131072 shorts = 65536 f
#define WS_WPK_LO   15414336   // 65536 f
#define WS_ZERO_FLOATS 13376   // counts..mask zeroed each call

// packed-weight offsets (shorts)
#define WOFF_O   49152
#define WOFF_W1  65536
#define WOFF_W2  98304

typedef __attribute__((ext_vector_type(8))) short bf8_t;
typedef __attribute__((ext_vector_type(4))) float f4_t;

__device__ inline short f2bf(float f) {
    union { float f; unsigned u; } v; v.f = f;
    unsigned r = (v.u + 0x7FFF + ((v.u >> 16) & 1)) >> 16;
    return (short)r;
}
__device__ inline float bf2f(short h) {
    union { unsigned u; float f; } v; v.u = ((unsigned)(unsigned short)h) << 16;
    return v.f;
}
__device__ inline unsigned pack2(short a, short b) {
    return (unsigned)(unsigned short)a | ((unsigned)(unsigned short)b << 16);
}
__device__ inline bf8_t bf8_from2(uint2 a, uint2 b) {
    bf8_t o;
    o[0]=(short)a.x; o[1]=(short)(a.x>>16); o[2]=(short)a.y; o[3]=(short)(a.y>>16);
    o[4]=(short)b.x; o[5]=(short)(b.x>>16); o[6]=(short)b.y; o[7]=(short)(b.y>>16);
    return o;
}

// ---------------- setup: counts -> offsets -> intra ----------------
__global__ __launch_bounds__(256) void setup_kernel(
    const int* __restrict__ batch, int* __restrict__ counts_o,
    int* __restrict__ offsets, int* __restrict__ intra)
{
    __shared__ int cnt[B_G];
    __shared__ int off[B_G];
    const int t = threadIdx.x;
    if (t < B_G) cnt[t] = 0;
    __syncthreads();
    for (int n = t; n < N_NODES; n += 256) atomicAdd(&cnt[batch[n]], 1);
    __syncthreads();
    if (t == 0) { int s = 0; for (int b = 0; b < B_G; ++b) { off[b] = s; s += cnt[b]; } }
    __syncthreads();
    if (t < B_G) { offsets[t] = off[t]; counts_o[t] = cnt[t]; }
    for (int n = t; n < N_NODES; n += 256) intra[n] = n - off[batch[n]];
}

// ---------------- prep: per-node pe -> dense pn/cn/kf + mask ----------------
__global__ __launch_bounds__(256) void prep_kernel(
    const float* __restrict__ pre, const float* __restrict__ pim,
    const int* __restrict__ batch, const int* __restrict__ intra,
    float* __restrict__ pn, float* __restrict__ cn,
    unsigned short* __restrict__ kf_hi, unsigned short* __restrict__ kf_lo,
    int* __restrict__ mask)
{
    const int idx = blockIdx.x * 256 + threadIdx.x;   // N_NODES*16 = 81920
    const int n = idx >> 4, dd = idx & 15;
    const int b = batch[n], m = intra[n];
    const size_t cell = (size_t)b * M_MAX + m;
    const float a = pre[(size_t)n * D_PE + dd], bb = pim[(size_t)n * D_PE + dd];
    const float p = sqrtf(a * a + bb * bb + EPS_PE);
    const float inv = 1.f / p;
    const float cr = a * inv, ci = bb * inv;
    pn[cell * 16 + dd] = p;
    cn[cell * 32 + dd]      = cr;
    cn[cell * 32 + 16 + dd] = ci;
    const size_t hb = cell * 64, lb = cell * 32;
    short crh = f2bf(cr), cih = f2bf(ci);
    kf_hi[hb + dd]      = (unsigned short)crh;
    kf_hi[hb + 16 + dd] = (unsigned short)cih;
    kf_hi[hb + 32 + dd] = (unsigned short)f2bf(p);
    kf_hi[hb + 48 + dd] = (dd == 0) ? (unsigned short)f2bf(1.f) : 0;
    kf_lo[lb + dd]      = (unsigned short)f2bf(cr - bf2f(crh));
    kf_lo[lb + 16 + dd] = (unsigned short)f2bf(ci - bf2f(cih));
    if (dd == 0) mask[cell] = 1;
}

// ---------------- weight packing (unchanged, validated) ----------------
__global__ __launch_bounds__(256) void wpack_kernel(
    const float* __restrict__ wq, const float* __restrict__ wk,
    const float* __restrict__ wv, const float* __restrict__ wo,
    const float* __restrict__ w1, const float* __restrict__ w2,
    unsigned short* __restrict__ hi, unsigned short* __restrict__ lo)
{
    const int tid = blockIdx.x * 256 + threadIdx.x;
    const int tile = tid >> 6, lane = tid & 63;
    const float* W; int N, ltile; size_t off;
    if (tile < 128) {
        const int wi = tile >> 5; ltile = tile & 31; N = 128;
        W = (wi == 0) ? wq : (wi == 1) ? wk : (wi == 2) ? wv : wo;
        off = (size_t)wi * 16384;
    } else if (tile < 192) { ltile = tile - 128; N = 256; W = w1; off = WOFF_W1; }
    else                   { ltile = tile - 192; N = 128; W = w2; off = WOFF_W2; }
    const int NT = N / 16;
    const int kt = ltile / NT, nt = ltile % NT;
    const int col = nt * 16 + (lane & 15);
    const int k0  = kt * 32 + (lane >> 4) * 8;
    bf8_t vhi, vlo;
    #pragma unroll
    for (int e = 0; e < 8; ++e) {
        const float v = W[(size_t)(k0 + e) * N + col];
        const short h = f2bf(v);
        vhi[e] = h; vlo[e] = f2bf(v - bf2f(h));
    }
    const size_t toff = off + ((size_t)ltile * 64 + lane) * 8;
    *(bf8_t*)(hi + toff) = vhi;
    *(bf8_t*)(lo + toff) = vlo;
}

// ---------------- MFMA core: acc[NT] = Arows @ W (split bf16) ----------------
template<int K, int N>
__device__ inline void mgemm_core(
    const float* __restrict__ Arow,  // points at A row `arow` (stride K)
    const unsigned short* __restrict__ hi, const unsigned short* __restrict__ lo,
    int lane, f4_t* acc)
{
    constexpr int NT = N / 16, KT = K / 32;
    const int g = lane >> 4;
    #pragma unroll
    for (int kt = 0; kt < KT; ++kt) {
        const float* ap = Arow + kt * 32 + g * 8;
        const float4 a0 = *(const float4*)ap;
        const float4 a1 = *(const float4*)(ap + 4);
        const float av[8] = {a0.x, a0.y, a0.z, a0.w, a1.x, a1.y, a1.z, a1.w};
        bf8_t ahi, alo;
        #pragma unroll
        for (int e = 0; e < 8; ++e) {
            const short h = f2bf(av[e]);
            ahi[e] = h; alo[e] = f2bf(av[e] - bf2f(h));
        }
        #pragma unroll
        for (int nt = 0; nt < NT; ++nt) {
            const size_t toff = ((size_t)(kt * NT + nt) * 64 + lane) * 8;
            const bf8_t bhi = *(const bf8_t*)(hi + toff);
            const bf8_t blo = *(const bf8_t*)(lo + toff);
            acc[nt] = __builtin_amdgcn_mfma_f32_16x16x32_bf16(ahi, bhi, acc[nt], 0, 0, 0);
            acc[nt] = __builtin_amdgcn_mfma_f32_16x16x32_bf16(alo, bhi, acc[nt], 0, 0, 0);
            acc[nt] = __builtin_amdgcn_mfma_f32_16x16x32_bf16(ahi, blo, acc[nt], 0, 0, 0);
        }
    }
}

// ---------------- QKV over nodes, scatter-write to dense ----------------
__global__ __launch_bounds__(256) void qkv_node_kernel(
    const float* __restrict__ x,
    const unsigned short* __restrict__ hi, const unsigned short* __restrict__ lo,
    const float* __restrict__ bq, const float* __restrict__ bk, const float* __restrict__ bv,
    const int* __restrict__ batch, const int* __restrict__ intra,
    float* __restrict__ qm, float* __restrict__ km, float* __restrict__ vm)
{
    const int sel = blockIdx.y;
    const float* bias = (sel == 0) ? bq : (sel == 1) ? bk : bv;
    float* out = (sel == 0) ? qm : (sel == 1) ? km : vm;
    const unsigned short* whi = hi + (size_t)sel * 16384;
    const unsigned short* wlo = lo + (size_t)sel * 16384;

    const int rb = blockIdx.x * 64;
    const int w = threadIdx.x >> 6, lane = threadIdx.x & 63;
    const int lj = lane & 15, g = lane >> 4;
    const int arow = rb + w * 16 + lj;   // node

    f4_t acc[8];
    #pragma unroll
    for (int nt = 0; nt < 8; ++nt) acc[nt] = (f4_t){0.f, 0.f, 0.f, 0.f};
    mgemm_core<128, 128>(x + (size_t)arow * 128, whi, wlo, lane, acc);

    const int orow0 = rb + w * 16 + g * 4;
    int dst[4];
    #pragma unroll
    for (int r = 0; r < 4; ++r) {
        const int nr = orow0 + r;
        dst[r] = batch[nr] * M_MAX + intra[nr];
    }
    #pragma unroll
    for (int nt = 0; nt < 8; ++nt) {
        const int col = nt * 16 + lj;
        const float bv_ = bias[col];
        #pragma unroll
        for (int r = 0; r < 4; ++r)
            out[(size_t)dst[r] * 128 + col] = acc[nt][r] + bv_;
    }
}

// ---------------- plain MFMA GEMM (ffn1) ----------------
template<int K, int N, bool RELU>
__global__ __launch_bounds__(256) void mgemm_kernel(
    const float* __restrict__ A,
    const unsigned short* __restrict__ hi, const unsigned short* __restrict__ lo,
    const float* __restrict__ bias, float* __restrict__ out)
{
    constexpr int NT = N / 16;
    const int rb = blockIdx.x * 64;
    const int w = threadIdx.x >> 6, lane = threadIdx.x & 63;
    const int lj = lane & 15, g = lane >> 4;
    const int arow = rb + w * 16 + lj;

    f4_t acc[NT];
    #pragma unroll
    for (int nt = 0; nt < NT; ++nt) acc[nt] = (f4_t){0.f, 0.f, 0.f, 0.f};
    mgemm_core<K, N>(A + (size_t)arow * K, hi, lo, lane, acc);

    const int orow0 = rb + w * 16 + g * 4;
    #pragma unroll
    for (int nt = 0; nt < NT; ++nt) {
        const int col = nt * 16 + lj;
        const float bv = bias[col];
        #pragma unroll
        for (int r = 0; r < 4; ++r) {
            float v = acc[nt][r] + bv;
            if (RELU) v = fmaxf(v, 0.f);
            out[(size_t)(orow0 + r) * N + col] = v;
        }
    }
}

// ---------------- GEMM + residual + LayerNorm fused (o-proj/ln2, ffn2/ln3) ----------------
// GATHER_A: A row = src[bm(node)] else A row = node. res: x (oproj) / hln (ffn2).
template<int K, bool GATHER_A>
__global__ __launch_bounds__(256) void gemm_res_ln_kernel(
    const float* __restrict__ A,
    const unsigned short* __restrict__ hi, const unsigned short* __restrict__ lo,
    const float* __restrict__ bias, const float* __restrict__ res,
    const int* __restrict__ batch, const int* __restrict__ intra,
    const float* __restrict__ lng, const float* __restrict__ lnb,
    float* __restrict__ out)
{
    __shared__ float sOut[64][133];
    __shared__ float red_s[64][4];
    __shared__ float red_q[64][4];

    const int rb = blockIdx.x * 64;
    const int w = threadIdx.x >> 6, lane = threadIdx.x & 63;
    const int lj = lane & 15, g = lane >> 4;
    const int arow = rb + w * 16 + lj;   // node
    const size_t asrc = GATHER_A ? (size_t)(batch[arow] * M_MAX + intra[arow]) : (size_t)arow;

    f4_t acc[8];
    #pragma unroll
    for (int nt = 0; nt < 8; ++nt) acc[nt] = (f4_t){0.f, 0.f, 0.f, 0.f};
    mgemm_core<K, 128>(A + asrc * K, hi, lo, lane, acc);

    const int lrow0 = w * 16 + g * 4;
    #pragma unroll
    for (int nt = 0; nt < 8; ++nt) {
        const int col = nt * 16 + lj;
        const float bv = bias[col];
        #pragma unroll
        for (int r = 0; r < 4; ++r)
            sOut[lrow0 + r][col] = acc[nt][r] + bv;
    }
    __syncthreads();

    const int row = threadIdx.x >> 2, seg = threadIdx.x & 3;
    const int n = rb + row;
    float s = 0.f, sq = 0.f;
    #pragma unroll
    for (int i = 0; i < 32; ++i) {
        const int c = 4 * i + seg;
        const float v = sOut[row][c] + res[(size_t)n * 128 + c];
        sOut[row][c] = v;
        s += v; sq += v * v;
    }
    red_s[row][seg] = s; red_q[row][seg] = sq;
    __syncthreads();
    s  = red_s[row][0] + red_s[row][1] + red_s[row][2] + red_s[row][3];
    sq = red_q[row][0] + red_q[row][1] + red_q[row][2] + red_q[row][3];
    const float mu  = s * (1.f / 128.f);
    const float var = sq * (1.f / 128.f) - mu * mu;
    const float sc  = rsqrtf(var + 1e-5f);
    #pragma unroll
    for (int i = 0; i < 32; ++i) {
        const int c = 4 * i + seg;
        out[(size_t)n * 128 + c] = (sOut[row][c] - mu) * sc * lng[c] + lnb[c];
    }
}

// ---------------- MFMA pairwise-bias kernel (+ i-exit, + j-tile bound) ----------------
__global__ __launch_bounds__(512) void bias_kernel(
    const float* __restrict__ cn, const float* __restrict__ pn,
    const unsigned short* __restrict__ kf_hi, const unsigned short* __restrict__ kf_lo,
    const float* __restrict__ w1, const float* __restrict__ b1,
    const float* __restrict__ w2, const float* __restrict__ b2,
    const int* __restrict__ counts,
    unsigned short* __restrict__ bias_out)
{
    const int b  = blockIdx.y;
    const int i0 = blockIdx.x * 16;
    const int cntb = counts[b];
    if (i0 >= cntb) return;
    const int jtN = (cntb + 15) >> 4;   // j-tiles with at least one real key

    __shared__ float sW1T[32][65];
    __shared__ float s_cn[16][32];
    __shared__ float s_pn[16][16];
    __shared__ uint2 s_scr[8][16][10];

    const int t  = threadIdx.x;

    for (int idx = t; idx < 2048; idx += 512) {
        int f = idx >> 5, hh = idx & 31;
        sW1T[hh][f] = w1[f * 32 + hh];
    }
    { int il = t >> 5, c = t & 31;
      s_cn[il][c] = cn[((size_t)(b * 256 + i0 + il)) * 32 + c]; }
    if (t < 256) { int il = t >> 4, dd = t & 15;
      s_pn[il][dd] = pn[((size_t)(b * 256 + i0 + il)) * 16 + dd]; }
    __syncthreads();

    const int w    = t >> 6;
    const int lane = t & 63;
    const int lj   = lane & 15;
    const int g    = lane >> 4;

    bf8_t a2f;
    #pragma unroll
    for (int e = 0; e < 8; ++e) {
        float v = (lj < 8) ? w2[(g * 8 + e) * 8 + lj] : 0.f;
        a2f[e] = f2bf(v);
    }
    float b2v0 = 0.f, b2v1 = 0.f, b2v2 = 0.f, b2v3 = 0.f;
    if (g < 2) { b2v0 = b2[g*4+0]; b2v1 = b2[g*4+1]; b2v2 = b2[g*4+2]; b2v3 = b2[g*4+3]; }

    for (int ii = 0; ii < 2; ++ii) {
        const int il = w * 2 + ii;
        const int i  = i0 + il;

        float vrow0 = b1[lj], vrow1 = b1[16 + lj];
        #pragma unroll
        for (int dd = 0; dd < 16; ++dd) {
            float p = s_pn[il][dd];
            vrow0 = fmaf(sW1T[lj][16 + dd],      p, vrow0);
            vrow1 = fmaf(sW1T[16 + lj][16 + dd], p, vrow1);
        }

        bf8_t a0hi0, a0lo0, a1f0, a0hi1, a0lo1, a1f1;
        #pragma unroll
        for (int e = 0; e < 8; ++e) {
            const int dd = (g & 1) * 8 + e;
            const float cr = s_cn[il][dd], ci = s_cn[il][16 + dd];
            {
                float wr = sW1T[lj][32 + dd], wi = sW1T[lj][48 + dd];
                float val = (g < 2) ? (wr * cr - wi * ci) : (wr * ci + wi * cr);
                short hi = f2bf(val);
                a0hi0[e] = hi; a0lo0[e] = f2bf(val - bf2f(hi));
                float v1 = (g < 2) ? sW1T[lj][g * 8 + e]
                                   : ((g == 2 && e == 0) ? vrow0 : 0.f);
                a1f0[e] = f2bf(v1);
            }
            {
                float wr = sW1T[16 + lj][32 + dd], wi = sW1T[16 + lj][48 + dd];
                float val = (g < 2) ? (wr * cr - wi * ci) : (wr * ci + wi * cr);
                short hi = f2bf(val);
                a0hi1[e] = hi; a0lo1[e] = f2bf(val - bf2f(hi));
                float v1 = (g < 2) ? sW1T[16 + lj][g * 8 + e]
                                   : ((g == 2 && e == 0) ? vrow1 : 0.f);
                a1f1[e] = f2bf(v1);
            }
        }

        for (int jt = 0; jt < jtN; ++jt) {
            const size_t node = (size_t)b * 256 + jt * 16 + lj;
            const bf8_t* ph = (const bf8_t*)(kf_hi + node * 64);
            const bf8_t* pl = (const bf8_t*)(kf_lo + node * 32);
            bf8_t b0hi = ph[g];
            bf8_t b0lo = pl[g];
            bf8_t b1f  = ph[4 + g];

            f4_t acc0 = {0.f, 0.f, 0.f, 0.f}, acc1 = {0.f, 0.f, 0.f, 0.f};
            acc0 = __builtin_amdgcn_mfma_f32_16x16x32_bf16(a0hi0, b0hi, acc0, 0, 0, 0);
            acc0 = __builtin_amdgcn_mfma_f32_16x16x32_bf16(a0hi0, b0lo, acc0, 0, 0, 0);
            acc0 = __builtin_amdgcn_mfma_f32_16x16x32_bf16(a0lo0, b0hi, acc0, 0, 0, 0);
            acc0 = __builtin_amdgcn_mfma_f32_16x16x32_bf16(a1f0,  b1f,  acc0, 0, 0, 0);
            acc1 = __builtin_amdgcn_mfma_f32_16x16x32_bf16(a0hi1, b0hi, acc1, 0, 0, 0);
            acc1 = __builtin_amdgcn_mfma_f32_16x16x32_bf16(a0hi1, b0lo, acc1, 0, 0, 0);
            acc1 = __builtin_amdgcn_mfma_f32_16x16x32_bf16(a0lo1, b0hi, acc1, 0, 0, 0);
            acc1 = __builtin_amdgcn_mfma_f32_16x16x32_bf16(a1f1,  b1f,  acc1, 0, 0, 0);

            uint2 w0, w1p;
            w0.x  = pack2(f2bf(fmaxf(acc0[0], 0.f)), f2bf(fmaxf(acc0[1], 0.f)));
            w0.y  = pack2(f2bf(fmaxf(acc0[2], 0.f)), f2bf(fmaxf(acc0[3], 0.f)));
            w1p.x = pack2(f2bf(fmaxf(acc1[0], 0.f)), f2bf(fmaxf(acc1[1], 0.f)));
            w1p.y = pack2(f2bf(fmaxf(acc1[2], 0.f)), f2bf(fmaxf(acc1[3], 0.f)));
            s_scr[w][lj][g]     = w0;
            s_scr[w][lj][4 + g] = w1p;
            __builtin_amdgcn_s_waitcnt(0);

            uint2 q0 = s_scr[w][lj][2 * g];
            uint2 q1 = s_scr[w][lj][2 * g + 1];
            bf8_t hb = bf8_from2(q0, q1);

            f4_t acc2 = {0.f, 0.f, 0.f, 0.f};
            acc2 = __builtin_amdgcn_mfma_f32_16x16x32_bf16(a2f, hb, acc2, 0, 0, 0);

            if (g < 2) {
                uint2 st;
                st.x = pack2(f2bf(acc2[0] + b2v0), f2bf(acc2[1] + b2v1));
                st.y = pack2(f2bf(acc2[2] + b2v2), f2bf(acc2[3] + b2v3));
                size_t idx = (((size_t)b * 256 + i) * 256 + jt * 16 + lj) * 8 + g * 4;
                *(uint2*)(bias_out + idx) = st;
            }
        }
    }
}

// ---------------- attention (QT=4, counts early-exit, PV j-bound) ----------------
__global__ __launch_bounds__(256) void attn_kernel(
    const float* __restrict__ qm, const float* __restrict__ km, const float* __restrict__ vm,
    const int* __restrict__ mask, const unsigned short* __restrict__ bias,
    const int* __restrict__ counts,
    float* __restrict__ o_att)
{
    const int b  = blockIdx.y;
    const int i0 = blockIdx.x * QT;
    const int cntb = counts[b];
    if (i0 >= cntb) return;
    const int t  = threadIdx.x;
    const int j  = t;

    __shared__ float s_q[QT][C_DIM];
    __shared__ float s_sc[QT][H_HEADS][SCP];

    for (int idx = t; idx < QT * C_DIM; idx += 256) {
        const int qi = idx >> 7, c = idx & 127;
        s_q[qi][c] = qm[((size_t)(b * 256 + i0 + qi)) * C_DIM + c];
    }
    __syncthreads();

    const int mj = mask[b * M_MAX + j];
    uint4 bu[QT];
    #pragma unroll
    for (int qi = 0; qi < QT; ++qi)
        bu[qi] = *(const uint4*)(bias + (((size_t)(b * 256 + i0 + qi)) * 256 + j) * 8);

    const float* krow = km + ((size_t)(b * 256 + j)) * C_DIM;
    #pragma unroll
    for (int h = 0; h < 8; ++h) {
        float kv[DH];
        #pragma unroll
        for (int q4 = 0; q4 < 4; ++q4) {
            float4 v = ((const float4*)(krow + h * DH))[q4];
            kv[q4*4+0]=v.x; kv[q4*4+1]=v.y; kv[q4*4+2]=v.z; kv[q4*4+3]=v.w;
        }
        #pragma unroll
        for (int qi = 0; qi < QT; ++qi) {
            float dot = 0.f;
            #pragma unroll
            for (int dd = 0; dd < DH; ++dd)
                dot = fmaf(s_q[qi][h * DH + dd], kv[dd], dot);
            const unsigned u = ((const unsigned*)&bu[qi])[h >> 1];
            const float bv = bf2f((short)((h & 1) ? (u >> 16) : (u & 0xffff)));
            s_sc[qi][h][j] = mj ? fmaf(dot, 0.25f, bv) : -1e9f;
        }
    }
    __syncthreads();

    {   // softmax: QT*8 = 32 rows of 256
        const int wave = t >> 6, lane = t & 63;
        for (int r = wave; r < QT * H_HEADS; r += 4) {
            float* row = ((float*)s_sc) + r * SCP;
            float x0 = row[lane], x1 = row[lane + 64], x2 = row[lane + 128], x3 = row[lane + 192];
            float mx = fmaxf(fmaxf(x0, x1), fmaxf(x2, x3));
            #pragma unroll
            for (int off = 32; off > 0; off >>= 1) mx = fmaxf(mx, __shfl_xor(mx, off, 64));
            float e0 = expf(x0 - mx), e1 = expf(x1 - mx), e2 = expf(x2 - mx), e3 = expf(x3 - mx);
            float s = e0 + e1 + e2 + e3;
            #pragma unroll
            for (int off = 32; off > 0; off >>= 1) s += __shfl_xor(s, off, 64);
            const float inv = 1.f / s;
            row[lane] = e0 * inv; row[lane + 64] = e1 * inv;
            row[lane + 128] = e2 * inv; row[lane + 192] = e3 * inv;
        }
    }
    __syncthreads();

    {   // PV: thread (c, gq) -> 2 query rows; j bounded by counts (probs exactly 0 beyond)
        const int c = t & 127;
        const int gq = t >> 7;
        const int h = c >> 4;
        const int qA = gq * 2, qB = gq * 2 + 1;
        const int jlim = (cntb + 3) & ~3;
        const float* vb = vm + (size_t)b * M_MAX * C_DIM + c;
        float a0 = 0.f, a1 = 0.f;
        for (int jj = 0; jj < jlim; jj += 4) {
            float4 pA = *(const float4*)&s_sc[qA][h][jj];
            float4 pB = *(const float4*)&s_sc[qB][h][jj];
            float v0 = vb[(size_t)(jj + 0) * C_DIM];
            float v1 = vb[(size_t)(jj + 1) * C_DIM];
            float v2 = vb[(size_t)(jj + 2) * C_DIM];
            float v3 = vb[(size_t)(jj + 3) * C_DIM];
            a0 = fmaf(pA.x, v0, a0); a0 = fmaf(pA.y, v1, a0);
            a0 = fmaf(pA.z, v2, a0); a0 = fmaf(pA.w, v3, a0);
            a1 = fmaf(pB.x, v0, a1); a1 = fmaf(pB.y, v1, a1);
            a1 = fmaf(pB.z, v2, a1); a1 = fmaf(pB.w, v3, a1);
        }
        o_att[((size_t)(b * 256 + i0 + qA)) * C_DIM + c] = a0;
        o_att[((size_t)(b * 256 + i0 + qB)) * C_DIM + c] = a1;
    }
}

// ---------------- launch ----------------
extern "C" void kernel_launch(void* const* d_in, const int* in_sizes, int n_in,
                              void* d_out, int out_size, void* d_ws, size_t ws_size,
                              hipStream_t stream)
{
    const float* x      = (const float*)d_in[0];
    const float* pe_re  = (const float*)d_in[1];
    const float* pe_im  = (const float*)d_in[2];
    const float* wq     = (const float*)d_in[3];
    const float* bq     = (const float*)d_in[4];
    const float* wk     = (const float*)d_in[5];
    const float* bk     = (const float*)d_in[6];
    const float* wv     = (const float*)d_in[7];
    const float* bv     = (const float*)d_in[8];
    const float* wo     = (const float*)d_in[9];
    const float* bo     = (const float*)d_in[10];
    const float* pe_w1  = (const float*)d_in[11];
    const float* pe_b1  = (const float*)d_in[12];
    const float* pe_w2  = (const float*)d_in[13];
    const float* pe_b2  = (const float*)d_in[14];
    const float* mlp_w1 = (const float*)d_in[15];
    const float* mlp_b1 = (const float*)d_in[16];
    const float* mlp_w2 = (const float*)d_in[17];
    const float* mlp_b2 = (const float*)d_in[18];
    const float* ln2_g  = (const float*)d_in[19];
    const float* ln2_b  = (const float*)d_in[20];
    const float* ln3_g  = (const float*)d_in[21];
    const float* ln3_b  = (const float*)d_in[22];
    const int*   batch  = (const int*)d_in[23];

    float* ws = (float*)d_ws;
    int*   counts  = (int*)(ws + WS_COUNTS);
    int*   offsets = (int*)(ws + WS_OFFSETS);
    int*   intra   = (int*)(ws + WS_INTRA);
    int*   mask    = (int*)(ws + WS_MASK);
    float* cn   = ws + WS_CN;
    float* pn   = ws + WS_PN;
    unsigned short* kf_hi = (unsigned short*)(ws + WS_KFHI);
    unsigned short* kf_lo = (unsigned short*)(ws + WS_KFLO);
    float* qm   = ws + WS_QM;
    float* km   = ws + WS_KM;
    float* vm   = ws + WS_VM;
    float* oatt = ws + WS_OATT;
    float* hln  = ws + WS_HLN;
    float* ffnh = ws + WS_FFNH;
    unsigned short* bias = (unsigned short*)(ws + WS_BIAS);
    unsigned short* wpk_hi = (unsigned short*)(ws + WS_WPK_HI);
    unsigned short* wpk_lo = (unsigned short*)(ws + WS_WPK_LO);
    float* outp = (float*)d_out;

    hipMemsetAsync(d_ws, 0, (size_t)WS_ZERO_FLOATS * sizeof(float), stream);

    setup_kernel<<<1, 256, 0, stream>>>(batch, counts, offsets, intra);
    wpack_kernel<<<64, 256, 0, stream>>>(wq, wk, wv, wo, mlp_w1, mlp_w2, wpk_hi, wpk_lo);
    prep_kernel<<<320, 256, 0, stream>>>(pe_re, pe_im, batch, intra, pn, cn, kf_hi, kf_lo, mask);

    qkv_node_kernel<<<dim3(80, 3), 256, 0, stream>>>(x, wpk_hi, wpk_lo, bq, bk, bv,
                                                     batch, intra, qm, km, vm);

    bias_kernel<<<dim3(16, 32), 512, 0, stream>>>(cn, pn, kf_hi, kf_lo,
                                                  pe_w1, pe_b1, pe_w2, pe_b2, counts, bias);

    attn_kernel<<<dim3(M_MAX / QT, B_G), 256, 0, stream>>>(qm, km, vm, mask, bias, counts, oatt);

    gemm_res_ln_kernel<128, true><<<80, 256, 0, stream>>>(
        oatt, wpk_hi + WOFF_O, wpk_lo + WOFF_O, bo, x, batch, intra, ln2_g, ln2_b, hln);

    mgemm_kernel<128, 256, true><<<80, 256, 0, stream>>>(
        hln, wpk_hi + WOFF_W1, wpk_lo + WOFF_W1, mlp_b1, ffnh);

    gemm_res_ln_kernel<256, false><<<80, 256, 0, stream>>>(
        ffnh, wpk_hi + WOFF_W2, wpk_lo + WOFF_W2, mlp_b2, hln, batch, intra, ln3_g, ln3_b, outp);
}